// Round 5
// baseline (1434.229 us; speedup 1.0000x reference)
//
#include <hip/hip_runtime.h>

// MNIST_RNN R5: R4's gate-parallel structure (8 waves x 64 samples/block,
// 4 waves/SIMD) but weights delivered from LDS as UNIFORM ds_read_b128
// broadcasts instead of s_load. Rationale: SMEM returns out-of-order =>
// any consume forces lgkmcnt(0) draining ALL scalar loads => no cross-
// batch pipelining (R3: 2900 w/t <-> 32.4k cyc/t; R4: 290 w/t cluster-
// serialized <-> 16k stall cyc/t). ds_read is in-order with partial
// lgkmcnt(N) waits and pipelines across the 4 resident waves/SIMD.
// W0 packed [40][40] (28 x + 10 h + 2 pad), W1 packed [40][20] (10+10);
// single-address b128 broadcasts are conflict-free. Biases hoisted to
// registers pre-loop. launch_bounds(512,4) pins VGPR<=128 for residency.

#define HDIM 10
#define DDIM 28
#define TSTEPS 28

typedef const __attribute__((address_space(1))) unsigned int gu32;
typedef __attribute__((address_space(3))) unsigned int lu32;

__device__ __forceinline__ void gld_lds16(const float* g, float4* l) {
    __builtin_amdgcn_global_load_lds((gu32*)g, (lu32*)l, 16, 0, 0);
}

__device__ __forceinline__ float fast_sigmoid(float v) {
    return __builtin_amdgcn_rcpf(1.0f + __expf(-v));
}
__device__ __forceinline__ float fast_tanh(float v) {
    return 2.0f * __builtin_amdgcn_rcpf(1.0f + __expf(-2.0f * v)) - 1.0f;
}

__global__ __launch_bounds__(512, 4) void lstm2_cls_kernel(
    const float* __restrict__ x,
    const float* __restrict__ w_ih0, const float* __restrict__ w_hh0,
    const float* __restrict__ b_ih0, const float* __restrict__ b_hh0,
    const float* __restrict__ w_ih1, const float* __restrict__ w_hh1,
    const float* __restrict__ b_ih1, const float* __restrict__ b_hh1,
    const float* __restrict__ w_cls, const float* __restrict__ b_cls,
    float* __restrict__ out)
{
    __shared__ float4 sx[2][7 * 64];   // x tiles, slot v*64+lane      14336 B
    __shared__ float g0[40 * 64];      // activated L0 gates [row][s]  10240 B
    __shared__ float g1[40 * 64];      //                              10240 B
    __shared__ float wW0[40 * 40];     // [row][28 x | 10 h | 2 pad]    6400 B
    __shared__ float wW1[40 * 20];     // [row][10 ih | 10 hh]          3200 B
    __shared__ float sb0[40], sb1[40]; //                                320 B

    const int tid  = threadIdx.x;
    const int lane = tid & 63;
    const int wid  = __builtin_amdgcn_readfirstlane(tid >> 6);
    const int b0   = blockIdx.x * 64;
    const int sample = b0 + lane;

    const int q     = wid >> 1;               // gate 0=i 1=f 2=g 3=o
    const int rbase = q * 10 + (wid & 1) * 5; // this wave's 5 rows
    const bool is_g = (q == 2);

    const float* xs = x + (size_t)sample * (TSTEPS * DDIM);

    // DMA t=0 x tile
    if (wid < 7) gld_lds16(xs + 4 * wid, &sx[0][wid * 64 + lane]);

    // stage packed weights into LDS (once)
    for (int i = tid; i < 40 * 40; i += 512) {
        const int r = i / 40, c = i - r * 40;
        float v = 0.0f;
        if (c < DDIM)            v = w_ih0[r * DDIM + c];
        else if (c < DDIM + HDIM) v = w_hh0[r * HDIM + (c - DDIM)];
        wW0[i] = v;
    }
    for (int i = tid; i < 40 * 20; i += 512) {
        const int r = i / 20, c = i - r * 20;
        wW1[i] = (c < HDIM) ? w_ih1[r * HDIM + c] : w_hh1[r * HDIM + (c - HDIM)];
    }
    for (int i = tid; i < 40; i += 512) {
        sb0[i] = b_ih0[i] + b_hh0[i];
        sb1[i] = b_ih1[i] + b_hh1[i];
    }

    float h0[HDIM], c0[HDIM], h1[HDIM], c1[HDIM];
    #pragma unroll
    for (int u = 0; u < HDIM; ++u) { h0[u] = c0[u] = h1[u] = c1[u] = 0.0f; }

    __syncthreads();   // weights + t=0 DMA visible

    // hoist this wave's biases into registers
    float bias0[5], bias1[5];
    #pragma unroll
    for (int k = 0; k < 5; ++k) {
        bias0[k] = sb0[rbase + k];
        bias1[k] = sb1[rbase + k];
    }

    #pragma unroll 1
    for (int t = 0; t < TSTEPS; ++t) {
        const int cur = t & 1;

        if (t + 1 < TSTEPS && wid < 7)
            gld_lds16(xs + (t + 1) * DDIM + 4 * wid, &sx[cur ^ 1][wid * 64 + lane]);

        // x row (7x ds_read_b128, lane-distinct conflict-free)
        float xr[DDIM];
        #pragma unroll
        for (int v = 0; v < 7; ++v) {
            const float4 qv = sx[cur][v * 64 + lane];
            xr[4*v+0] = qv.x; xr[4*v+1] = qv.y; xr[4*v+2] = qv.z; xr[4*v+3] = qv.w;
        }

        // ---- P1/L0: 5 rows, weights via uniform b128 broadcast ----
        {
            float a[5];
            #pragma unroll
            for (int k = 0; k < 5; ++k) {
                const float4* wp = (const float4*)&wW0[(rbase + k) * 40];
                float acc = bias0[k];
                #pragma unroll
                for (int v = 0; v < 7; ++v) {
                    const float4 w = wp[v];
                    acc += xr[4*v+0]*w.x + xr[4*v+1]*w.y + xr[4*v+2]*w.z + xr[4*v+3]*w.w;
                }
                { const float4 w = wp[7]; acc += h0[0]*w.x + h0[1]*w.y + h0[2]*w.z + h0[3]*w.w; }
                { const float4 w = wp[8]; acc += h0[4]*w.x + h0[5]*w.y + h0[6]*w.z + h0[7]*w.w; }
                { const float4 w = wp[9]; acc += h0[8]*w.x + h0[9]*w.y; }
                a[k] = acc;
            }
            #pragma unroll
            for (int k = 0; k < 5; ++k)
                g0[(rbase + k) * 64 + lane] = is_g ? fast_tanh(a[k]) : fast_sigmoid(a[k]);
        }
        __syncthreads();   // BAR-A

        // ---- P2/L0: redundant c0/h0 update ----
        #pragma unroll
        for (int u = 0; u < HDIM; ++u) {
            const float iv = g0[(     u) * 64 + lane];
            const float fv = g0[(10 + u) * 64 + lane];
            const float gv = g0[(20 + u) * 64 + lane];
            const float ov = g0[(30 + u) * 64 + lane];
            const float c  = fv * c0[u] + iv * gv;
            c0[u] = c;
            h0[u] = ov * fast_tanh(c);
        }

        // ---- P1/L1: 5 rows, weights via uniform b128 broadcast ----
        {
            float a[5];
            #pragma unroll
            for (int k = 0; k < 5; ++k) {
                const float4* wp = (const float4*)&wW1[(rbase + k) * 20];
                float acc = bias1[k];
                { const float4 w = wp[0]; acc += h0[0]*w.x + h0[1]*w.y + h0[2]*w.z + h0[3]*w.w; }
                { const float4 w = wp[1]; acc += h0[4]*w.x + h0[5]*w.y + h0[6]*w.z + h0[7]*w.w; }
                { const float4 w = wp[2]; acc += h0[8]*w.x + h0[9]*w.y + h1[0]*w.z + h1[1]*w.w; }
                { const float4 w = wp[3]; acc += h1[2]*w.x + h1[3]*w.y + h1[4]*w.z + h1[5]*w.w; }
                { const float4 w = wp[4]; acc += h1[6]*w.x + h1[7]*w.y + h1[8]*w.z + h1[9]*w.w; }
                a[k] = acc;
            }
            #pragma unroll
            for (int k = 0; k < 5; ++k)
                g1[(rbase + k) * 64 + lane] = is_g ? fast_tanh(a[k]) : fast_sigmoid(a[k]);
        }
        __syncthreads();   // BAR-B (also drains DMA prefetch)

        // ---- P2/L1: redundant c1/h1 update ----
        #pragma unroll
        for (int u = 0; u < HDIM; ++u) {
            const float iv = g1[(     u) * 64 + lane];
            const float fv = g1[(10 + u) * 64 + lane];
            const float gv = g1[(20 + u) * 64 + lane];
            const float ov = g1[(30 + u) * 64 + lane];
            const float c  = fv * c1[u] + iv * gv;
            c1[u] = c;
            h1[u] = ov * fast_tanh(c);
        }
    }

    // ---- classifier: waves 0,1 produce 5 outputs each ----
    if (wid < 2) {
        #pragma unroll
        for (int k = 0; k < 5; ++k) {
            const int o = wid * 5 + k;
            float a = b_cls[o];
            const float* wc = w_cls + o * HDIM;
            #pragma unroll
            for (int j = 0; j < HDIM; ++j) a += h1[j] * wc[j];
            out[(size_t)sample * 10 + o] = a;
        }
    }
}

extern "C" void kernel_launch(void* const* d_in, const int* in_sizes, int n_in,
                              void* d_out, int out_size, void* d_ws, size_t ws_size,
                              hipStream_t stream) {
    const float* x     = (const float*)d_in[0];
    const float* w_ih0 = (const float*)d_in[1];
    const float* w_hh0 = (const float*)d_in[2];
    const float* b_ih0 = (const float*)d_in[3];
    const float* b_hh0 = (const float*)d_in[4];
    const float* w_ih1 = (const float*)d_in[5];
    const float* w_hh1 = (const float*)d_in[6];
    const float* b_ih1 = (const float*)d_in[7];
    const float* b_hh1 = (const float*)d_in[8];
    const float* w_cls = (const float*)d_in[9];
    const float* b_cls = (const float*)d_in[10];
    float* out = (float*)d_out;

    const int B = in_sizes[0] / (TSTEPS * DDIM);   // 32768
    const int grid = B / 64;                       // 512 blocks, 8 waves each

    hipLaunchKernelGGL(lstm2_cls_kernel, dim3(grid), dim3(512), 0, stream,
                       x, w_ih0, w_hh0, b_ih0, b_hh0,
                       w_ih1, w_hh1, b_ih1, b_hh1,
                       w_cls, b_cls, out);
}

// Round 6
// 283.190 us; speedup vs baseline: 5.0646x; 5.0646x over previous
//
#include <hip/hip_runtime.h>

// MNIST_RNN R6 = R5 with the spill confound removed.
// R5's 1353us was pure scratch traffic: __launch_bounds__(512,4) acts as
// min-4-BLOCKS/CU (CUDA semantics) -> 32 waves/CU -> 64-VGPR cap (VGPR_Count
// was exactly 64) -> ds_read weight vectors + xr spilled (WRITE 3.5GB).
// Fix: (512,2) -> 16 waves/CU -> 128-VGPR cap, matching the 2-blocks/CU grid.
// Structure: 8 gate-parallel waves x 64 samples/block; weights from LDS as
// uniform ds_read_b128 broadcasts (in-order lgkmcnt, pipelines across waves,
// bypasses the ~0.2 float/cyc/CU scalar-pipe law seen in R3/R4); activated
// gates exchanged via LDS [row][sample]; redundant P2 keeps h in registers.

#define HDIM 10
#define DDIM 28
#define TSTEPS 28

typedef const __attribute__((address_space(1))) unsigned int gu32;
typedef __attribute__((address_space(3))) unsigned int lu32;

__device__ __forceinline__ void gld_lds16(const float* g, float4* l) {
    __builtin_amdgcn_global_load_lds((gu32*)g, (lu32*)l, 16, 0, 0);
}

__device__ __forceinline__ float fast_sigmoid(float v) {
    return __builtin_amdgcn_rcpf(1.0f + __expf(-v));
}
__device__ __forceinline__ float fast_tanh(float v) {
    return 2.0f * __builtin_amdgcn_rcpf(1.0f + __expf(-2.0f * v)) - 1.0f;
}

__global__ __launch_bounds__(512, 2) void lstm2_cls_kernel(
    const float* __restrict__ x,
    const float* __restrict__ w_ih0, const float* __restrict__ w_hh0,
    const float* __restrict__ b_ih0, const float* __restrict__ b_hh0,
    const float* __restrict__ w_ih1, const float* __restrict__ w_hh1,
    const float* __restrict__ b_ih1, const float* __restrict__ b_hh1,
    const float* __restrict__ w_cls, const float* __restrict__ b_cls,
    float* __restrict__ out)
{
    __shared__ float4 sx[2][7 * 64];   // x tiles, slot v*64+lane      14336 B
    __shared__ float g0[40 * 64];      // activated L0 gates [row][s]  10240 B
    __shared__ float g1[40 * 64];      //                              10240 B
    __shared__ float wW0[40 * 40];     // [row][28 x | 10 h | 2 pad]    6400 B
    __shared__ float wW1[40 * 20];     // [row][10 ih | 10 hh]          3200 B
    __shared__ float sb0[40], sb1[40]; //                                320 B

    const int tid  = threadIdx.x;
    const int lane = tid & 63;
    const int wid  = __builtin_amdgcn_readfirstlane(tid >> 6);
    const int b0   = blockIdx.x * 64;
    const int sample = b0 + lane;

    const int q     = wid >> 1;               // gate 0=i 1=f 2=g 3=o
    const int rbase = q * 10 + (wid & 1) * 5; // this wave's 5 rows
    const bool is_g = (q == 2);

    const float* xs = x + (size_t)sample * (TSTEPS * DDIM);

    // DMA t=0 x tile
    if (wid < 7) gld_lds16(xs + 4 * wid, &sx[0][wid * 64 + lane]);

    // stage packed weights into LDS (once)
    for (int i = tid; i < 40 * 40; i += 512) {
        const int r = i / 40, c = i - r * 40;
        float v = 0.0f;
        if (c < DDIM)             v = w_ih0[r * DDIM + c];
        else if (c < DDIM + HDIM) v = w_hh0[r * HDIM + (c - DDIM)];
        wW0[i] = v;
    }
    for (int i = tid; i < 40 * 20; i += 512) {
        const int r = i / 20, c = i - r * 20;
        wW1[i] = (c < HDIM) ? w_ih1[r * HDIM + c] : w_hh1[r * HDIM + (c - HDIM)];
    }
    for (int i = tid; i < 40; i += 512) {
        sb0[i] = b_ih0[i] + b_hh0[i];
        sb1[i] = b_ih1[i] + b_hh1[i];
    }

    float h0[HDIM], c0[HDIM], h1[HDIM], c1[HDIM];
    #pragma unroll
    for (int u = 0; u < HDIM; ++u) { h0[u] = c0[u] = h1[u] = c1[u] = 0.0f; }

    __syncthreads();   // weights + t=0 DMA visible

    // hoist this wave's biases into registers
    float bias0[5], bias1[5];
    #pragma unroll
    for (int k = 0; k < 5; ++k) {
        bias0[k] = sb0[rbase + k];
        bias1[k] = sb1[rbase + k];
    }

    #pragma unroll 1
    for (int t = 0; t < TSTEPS; ++t) {
        const int cur = t & 1;

        if (t + 1 < TSTEPS && wid < 7)
            gld_lds16(xs + (t + 1) * DDIM + 4 * wid, &sx[cur ^ 1][wid * 64 + lane]);

        // x row (7x ds_read_b128, lane-distinct conflict-free)
        float xr[DDIM];
        #pragma unroll
        for (int v = 0; v < 7; ++v) {
            const float4 qv = sx[cur][v * 64 + lane];
            xr[4*v+0] = qv.x; xr[4*v+1] = qv.y; xr[4*v+2] = qv.z; xr[4*v+3] = qv.w;
        }

        // ---- P1/L0: 5 rows, weights via uniform b128 broadcast;
        //      activation applied per-row immediately (short live ranges) ----
        #pragma unroll
        for (int k = 0; k < 5; ++k) {
            const float4* wp = (const float4*)&wW0[(rbase + k) * 40];
            float acc = bias0[k];
            #pragma unroll
            for (int v = 0; v < 7; ++v) {
                const float4 w = wp[v];
                acc += xr[4*v+0]*w.x + xr[4*v+1]*w.y + xr[4*v+2]*w.z + xr[4*v+3]*w.w;
            }
            { const float4 w = wp[7]; acc += h0[0]*w.x + h0[1]*w.y + h0[2]*w.z + h0[3]*w.w; }
            { const float4 w = wp[8]; acc += h0[4]*w.x + h0[5]*w.y + h0[6]*w.z + h0[7]*w.w; }
            { const float4 w = wp[9]; acc += h0[8]*w.x + h0[9]*w.y; }
            g0[(rbase + k) * 64 + lane] = is_g ? fast_tanh(acc) : fast_sigmoid(acc);
        }
        __syncthreads();   // BAR-A

        // ---- P2/L0: redundant c0/h0 update ----
        #pragma unroll
        for (int u = 0; u < HDIM; ++u) {
            const float iv = g0[(     u) * 64 + lane];
            const float fv = g0[(10 + u) * 64 + lane];
            const float gv = g0[(20 + u) * 64 + lane];
            const float ov = g0[(30 + u) * 64 + lane];
            const float c  = fv * c0[u] + iv * gv;
            c0[u] = c;
            h0[u] = ov * fast_tanh(c);
        }

        // ---- P1/L1: 5 rows, weights via uniform b128 broadcast ----
        #pragma unroll
        for (int k = 0; k < 5; ++k) {
            const float4* wp = (const float4*)&wW1[(rbase + k) * 20];
            float acc = bias1[k];
            { const float4 w = wp[0]; acc += h0[0]*w.x + h0[1]*w.y + h0[2]*w.z + h0[3]*w.w; }
            { const float4 w = wp[1]; acc += h0[4]*w.x + h0[5]*w.y + h0[6]*w.z + h0[7]*w.w; }
            { const float4 w = wp[2]; acc += h0[8]*w.x + h0[9]*w.y + h1[0]*w.z + h1[1]*w.w; }
            { const float4 w = wp[3]; acc += h1[2]*w.x + h1[3]*w.y + h1[4]*w.z + h1[5]*w.w; }
            { const float4 w = wp[4]; acc += h1[6]*w.x + h1[7]*w.y + h1[8]*w.z + h1[9]*w.w; }
            g1[(rbase + k) * 64 + lane] = is_g ? fast_tanh(acc) : fast_sigmoid(acc);
        }
        __syncthreads();   // BAR-B (also drains DMA prefetch)

        // ---- P2/L1: redundant c1/h1 update ----
        #pragma unroll
        for (int u = 0; u < HDIM; ++u) {
            const float iv = g1[(     u) * 64 + lane];
            const float fv = g1[(10 + u) * 64 + lane];
            const float gv = g1[(20 + u) * 64 + lane];
            const float ov = g1[(30 + u) * 64 + lane];
            const float c  = fv * c1[u] + iv * gv;
            c1[u] = c;
            h1[u] = ov * fast_tanh(c);
        }
    }

    // ---- classifier: waves 0,1 produce 5 outputs each ----
    if (wid < 2) {
        #pragma unroll
        for (int k = 0; k < 5; ++k) {
            const int o = wid * 5 + k;
            float a = b_cls[o];
            const float* wc = w_cls + o * HDIM;
            #pragma unroll
            for (int j = 0; j < HDIM; ++j) a += h1[j] * wc[j];
            out[(size_t)sample * 10 + o] = a;
        }
    }
}

extern "C" void kernel_launch(void* const* d_in, const int* in_sizes, int n_in,
                              void* d_out, int out_size, void* d_ws, size_t ws_size,
                              hipStream_t stream) {
    const float* x     = (const float*)d_in[0];
    const float* w_ih0 = (const float*)d_in[1];
    const float* w_hh0 = (const float*)d_in[2];
    const float* b_ih0 = (const float*)d_in[3];
    const float* b_hh0 = (const float*)d_in[4];
    const float* w_ih1 = (const float*)d_in[5];
    const float* w_hh1 = (const float*)d_in[6];
    const float* b_ih1 = (const float*)d_in[7];
    const float* b_hh1 = (const float*)d_in[8];
    const float* w_cls = (const float*)d_in[9];
    const float* b_cls = (const float*)d_in[10];
    float* out = (float*)d_out;

    const int B = in_sizes[0] / (TSTEPS * DDIM);   // 32768
    const int grid = B / 64;                       // 512 blocks, 8 waves each

    hipLaunchKernelGGL(lstm2_cls_kernel, dim3(grid), dim3(512), 0, stream,
                       x, w_ih0, w_hh0, b_ih0, b_hh0,
                       w_ih1, w_hh1, b_ih1, b_hh1,
                       w_cls, b_cls, out);
}